// Round 6
// baseline (183.827 us; speedup 1.0000x reference)
//
#include <hip/hip_runtime.h>

#define BATCH 16
#define SEQ   4096
#define DIM   64
#define WIN   512

constexpr int BM = 64;        // q rows per block (4 independent waves, 16 rows each)
constexpr int BN = 64;        // keys per round
constexpr int NTHREADS = 256;

constexpr float QSCALE  = 0.125f * 1.44269504088896340736f;
constexpr float MASKVAL = -3.0e38f;
constexpr float DEFER_THR = 8.0f;

typedef _Float16 f16x2 __attribute__((ext_vector_type(2)));
typedef _Float16 f16x4 __attribute__((ext_vector_type(4)));
typedef _Float16 f16x8 __attribute__((ext_vector_type(8)));
typedef float    f32x4 __attribute__((ext_vector_type(4)));

__device__ __forceinline__ f16x2 pk2(float a, float b) {
    return __builtin_bit_cast(f16x2, __builtin_amdgcn_cvt_pkrtz(a, b));
}

// ---------- pre-pass: K fp32 -> f16 [b][s][d]; V fp32 -> f16 transposed [b][d][s] ----------
__global__ __launch_bounds__(256)
void prep_kernel(const float* __restrict__ kg, const float* __restrict__ vg,
                 _Float16* __restrict__ k16, _Float16* __restrict__ vt16, int do_k) {
    __shared__ _Float16 tile[64][72];   // [s_local][d], padded
    const int t  = threadIdx.x;
    const int b  = blockIdx.y;
    const int s0 = blockIdx.x * 64;
    const int r  = t >> 4;              // 0..15
    const int c4 = (t & 15) * 4;        // 0..60

    const float* vbp = vg + ((size_t)b * SEQ + s0) * DIM;
    #pragma unroll
    for (int i = 0; i < 4; ++i) {
        const int row = r + i * 16;
        const float4 v4 = *(const float4*)&vbp[(size_t)row * DIM + c4];
        union { f16x4 h4; f16x2 h2[2]; } u;
        u.h2[0] = pk2(v4.x, v4.y); u.h2[1] = pk2(v4.z, v4.w);
        *(f16x4*)&tile[row][c4] = u.h4;
    }
    if (do_k) {
        const float* kbp = kg + ((size_t)b * SEQ + s0) * DIM;
        _Float16*    kop = k16 + ((size_t)b * SEQ + s0) * DIM;
        #pragma unroll
        for (int i = 0; i < 4; ++i) {
            const int row = r + i * 16;
            const float4 v4 = *(const float4*)&kbp[(size_t)row * DIM + c4];
            union { f16x4 h4; f16x2 h2[2]; } u;
            u.h2[0] = pk2(v4.x, v4.y); u.h2[1] = pk2(v4.z, v4.w);
            *(f16x4*)&kop[(size_t)row * DIM + c4] = u.h4;
        }
    }
    __syncthreads();
    // write VT[b][d][s0..s0+63]: thread -> d = t>>2, s-chunk = (t&3)*16
    const int d   = t >> 2;
    const int sc_ = (t & 3) * 16;
    _Float16* vop = vt16 + ((size_t)b * DIM + d) * SEQ + s0 + sc_;
    union { f16x8 h8; _Float16 e[8]; } w0, w1;
    #pragma unroll
    for (int j = 0; j < 8; ++j) { w0.e[j] = tile[sc_ + j][d]; w1.e[j] = tile[sc_ + 8 + j][d]; }
    *(f16x8*)&vop[0] = w0.h8;
    *(f16x8*)&vop[8] = w1.h8;
}

// ---------- main: no LDS, no barriers; frags straight from global (L1/L2-served) ----------
template<bool K16EN>
__global__ __launch_bounds__(NTHREADS, 4)
void swa_main(const float* __restrict__ qg, const float* __restrict__ kg,
              float* __restrict__ outg,
              const _Float16* __restrict__ k16, const _Float16* __restrict__ vt16) {
    const int tid  = threadIdx.x;
    const int lane = tid & 63;
    const int wave = tid >> 6;     // 0..3
    const int lr   = lane & 15;
    const int quad = lane >> 4;

    // chunked XCD swizzle: 8 consecutive qblks of one batch per XCD chunk
    static_assert(SEQ / BM == 64 && BATCH == 16, "swizzle assumes 1024 blocks");
    const int lin    = blockIdx.x;         // 0..1023
    const int xcd    = lin & 7;
    const int slot   = lin >> 3;           // 0..127
    const int member = slot & 7;
    const int gchunk = (slot >> 3) * 8 + xcd;      // bijective 0..127
    const int b      = gchunk >> 3;                // 16 batches
    const int qblk   = (gchunk & 7) * 8 + member;  // 64 qblks

    const int qrow0 = qblk * BM;
    const int wr0   = qrow0 + wave * 16;
    const int q     = wr0 + lr;            // this lane's q column (S^T layout)

    const float*    qb  = qg  + (size_t)b * SEQ * DIM;
    const float*    kb  = kg  + (size_t)b * SEQ * DIM;
    float*          ob  = outg + (size_t)b * SEQ * DIM;
    const _Float16* kfb = K16EN ? (k16 + (size_t)b * SEQ * DIM) : nullptr;
    const _Float16* vtb = vt16 + (size_t)b * DIM * SEQ;

    // ---- Q B-frags straight from global into registers (fp32 -> f16 once) ----
    const float* qp = qb + (size_t)q * DIM + quad * 8;
    const float4 a0 = *(const float4*)(qp + 0);
    const float4 a1 = *(const float4*)(qp + 4);
    const float4 a2 = *(const float4*)(qp + 32);
    const float4 a3 = *(const float4*)(qp + 36);
    union { f16x8 v; f16x2 h[4]; } uq0, uq1;
    uq0.h[0] = pk2(a0.x * QSCALE, a0.y * QSCALE);
    uq0.h[1] = pk2(a0.z * QSCALE, a0.w * QSCALE);
    uq0.h[2] = pk2(a1.x * QSCALE, a1.y * QSCALE);
    uq0.h[3] = pk2(a1.z * QSCALE, a1.w * QSCALE);
    uq1.h[0] = pk2(a2.x * QSCALE, a2.y * QSCALE);
    uq1.h[1] = pk2(a2.z * QSCALE, a2.w * QSCALE);
    uq1.h[2] = pk2(a3.x * QSCALE, a3.y * QSCALE);
    uq1.h[3] = pk2(a3.z * QSCALE, a3.w * QSCALE);
    const f16x8 qf0 = uq0.v, qf1 = uq1.v;

    f32x4 o[4];
    #pragma unroll
    for (int mi = 0; mi < 4; ++mi) o[mi] = (f32x4){0.f, 0.f, 0.f, 0.f};
    float m_run = -1e30f, l_run = 0.f;

    // per-WAVE tile range (waves fully independent now)
    const int lo = (wr0 > (WIN - 1)) ? wr0 - (WIN - 1) : 0;
    const int t0 = lo >> 6;
    const int t1 = (wr0 + 15) >> 6;

    for (int t = t0; t <= t1; ++t) {
        const int kbase = t * BN;
        const int u     = (wr0 - kbase) >> 4;        // >= 0 (multiples of 16)
        const int mtlo  = (u - 32 > 0) ? u - 32 : 0;
        const int mthi  = (u < 3) ? u : 3;

        // ---- S^T = K * Q^T over active m-tiles; K frags direct from global ----
        f32x4 sc[4];
        #pragma unroll
        for (int mt = 0; mt < 4; ++mt) {
            if (mt >= mtlo && mt <= mthi) {
                f16x8 kf0, kf1;
                if constexpr (K16EN) {
                    const _Float16* kp = kfb + (size_t)(kbase + mt * 16 + lr) * DIM + quad * 8;
                    kf0 = *(const f16x8*)(kp + 0);
                    kf1 = *(const f16x8*)(kp + 32);
                } else {
                    const float* kp = kb + (size_t)(kbase + mt * 16 + lr) * DIM + quad * 8;
                    const float4 x0 = *(const float4*)(kp + 0);
                    const float4 x1 = *(const float4*)(kp + 4);
                    const float4 x2 = *(const float4*)(kp + 32);
                    const float4 x3 = *(const float4*)(kp + 36);
                    union { f16x8 v; f16x2 h[4]; } u0, u1;
                    u0.h[0] = pk2(x0.x, x0.y); u0.h[1] = pk2(x0.z, x0.w);
                    u0.h[2] = pk2(x1.x, x1.y); u0.h[3] = pk2(x1.z, x1.w);
                    u1.h[0] = pk2(x2.x, x2.y); u1.h[1] = pk2(x2.z, x2.w);
                    u1.h[2] = pk2(x3.x, x3.y); u1.h[3] = pk2(x3.z, x3.w);
                    kf0 = u0.v; kf1 = u1.v;
                }
                f32x4 s = (f32x4){0.f, 0.f, 0.f, 0.f};
                s = __builtin_amdgcn_mfma_f32_16x16x32_f16(kf0, qf0, s, 0, 0, 0);
                s = __builtin_amdgcn_mfma_f32_16x16x32_f16(kf1, qf1, s, 0, 0, 0);
                sc[mt] = s;
            }
        }

        // ---- mask only on window-edge tiles (wave-uniform branch) ----
        const bool edge = (kbase + mtlo * 16 < wr0 + 15 - (WIN - 1)) ||
                          (kbase + mthi * 16 + 15 > wr0);
        if (edge) {
            #pragma unroll
            for (int mt = 0; mt < 4; ++mt) {
                if (mt >= mtlo && mt <= mthi) {
                    #pragma unroll
                    for (int r = 0; r < 4; ++r) {
                        const int key = kbase + mt * 16 + quad * 4 + r;
                        sc[mt][r] = ((unsigned)(q - key) < (unsigned)WIN) ? sc[mt][r] : MASKVAL;
                    }
                }
            }
        }

        // ---- row max over active tiles, then cross-quad ----
        float pm = MASKVAL;
        #pragma unroll
        for (int mt = 0; mt < 4; ++mt) {
            if (mt >= mtlo && mt <= mthi) {
                pm = fmaxf(pm, fmaxf(fmaxf(sc[mt][0], sc[mt][1]),
                                     fmaxf(sc[mt][2], sc[mt][3])));
            }
        }
        pm = fmaxf(pm, __shfl_xor(pm, 16));
        pm = fmaxf(pm, __shfl_xor(pm, 32));

        // ---- T13 defer-rescale ----
        if (__any(pm > m_run + DEFER_THR)) {
            const float mn    = fmaxf(m_run, pm);
            const float alpha = exp2f(m_run - mn);
            m_run = mn;
            l_run *= alpha;
            #pragma unroll
            for (int mi = 0; mi < 4; ++mi) o[mi] = o[mi] * alpha;
        }

        f16x4 pb[4];
        float ls = 0.f;
        #pragma unroll
        for (int nt = 0; nt < 4; ++nt) {
            if (nt >= mtlo && nt <= mthi) {
                const float p0 = exp2f(sc[nt][0] - m_run);
                const float p1 = exp2f(sc[nt][1] - m_run);
                const float p2 = exp2f(sc[nt][2] - m_run);
                const float p3 = exp2f(sc[nt][3] - m_run);
                ls += (p0 + p1) + (p2 + p3);
                union { f16x4 v; f16x2 h[2]; } up;
                up.h[0] = pk2(p0, p1);
                up.h[1] = pk2(p2, p3);
                pb[nt] = up.v;
            }
        }
        l_run += ls;

        // ---- O^T += V^T * P^T ; V^T frags direct from global VT16[b][d][s] ----
        #pragma unroll
        for (int nt = 0; nt < 4; ++nt) {
            if (nt >= mtlo && nt <= mthi) {
                #pragma unroll
                for (int mi = 0; mi < 4; ++mi) {
                    const f16x4 vf = *(const f16x4*)&vtb[(size_t)(mi * 16 + lr) * SEQ
                                                          + kbase + nt * 16 + quad * 4];
                    o[mi] = __builtin_amdgcn_mfma_f32_16x16x16f16(vf, pb[nt], o[mi], 0, 0, 0);
                }
            }
        }
    }

    // ---- epilogue: l reduce across quads, normalize, DIRECT stores ----
    // o[mi][j] = O^T[d = mi*16 + quad*4 + j][q] -> contiguous in d: one float4/mi
    l_run += __shfl_xor(l_run, 16);
    l_run += __shfl_xor(l_run, 32);
    const float inv = 1.0f / l_run;
    #pragma unroll
    for (int mi = 0; mi < 4; ++mi) {
        float4 st;
        st.x = o[mi][0] * inv; st.y = o[mi][1] * inv;
        st.z = o[mi][2] * inv; st.w = o[mi][3] * inv;
        *(float4*)&ob[(size_t)q * DIM + mi * 16 + quad * 4] = st;
    }
}

extern "C" void kernel_launch(void* const* d_in, const int* in_sizes, int n_in,
                              void* d_out, int out_size, void* d_ws, size_t ws_size,
                              hipStream_t stream) {
    (void)in_sizes; (void)n_in; (void)out_size;
    const float* q = (const float*)d_in[0];
    const float* k = (const float*)d_in[1];
    const float* v = (const float*)d_in[2];
    float* out = (float*)d_out;

    const size_t KVB = (size_t)BATCH * SEQ * DIM * sizeof(_Float16);  // 8.39 MB
    _Float16* vt16 = (_Float16*)d_ws;
    const bool k16en = ws_size >= 2 * KVB;   // K16 only if workspace allows
    _Float16* k16 = k16en ? (_Float16*)((char*)d_ws + KVB) : nullptr;

    prep_kernel<<<dim3(SEQ / 64, BATCH), dim3(256), 0, stream>>>(k, v, k16, vt16, (int)k16en);
    if (k16en)
        swa_main<true ><<<dim3(BATCH * SEQ / BM), dim3(NTHREADS), 0, stream>>>(q, k, out, k16, vt16);
    else
        swa_main<false><<<dim3(BATCH * SEQ / BM), dim3(NTHREADS), 0, stream>>>(q, k, out, k16, vt16);
}

// Round 8
// 114.724 us; speedup vs baseline: 1.6023x; 1.6023x over previous
//
#include <hip/hip_runtime.h>

#define BATCH 16
#define SEQ   4096
#define DIM   64
#define WIN   512

constexpr int BM = 128;       // q rows per block: 4 waves x 32 q-rows each
constexpr int BN = 64;        // keys per tile
constexpr int NTHREADS = 256; // 4 waves
constexpr int KS  = DIM + 8;  // Ksh row stride (f16)
constexpr int VSP = 20;       // V panel row stride (16 keys + 4 pad) -> <=2-way banks
constexpr int OS  = DIM + 4;  // Osh row stride (f32)
constexpr int KBYTES   = BN * KS * 2;        // 9216
constexpr int VPANEL   = DIM * VSP * 2;      // 2560 B per 16-key panel
constexpr int VBYTES   = 4 * VPANEL;         // 10240
constexpr int BUFBYTES = KBYTES + VBYTES;    // 19456
constexpr int SMEMBYTES = 2 * BUFBYTES;      // 38912 >= epilogue 4*32*OS*4 = 34816

constexpr float QSCALE  = 0.125f * 1.44269504088896340736f;
constexpr float MASKVAL = -3.0e38f;   // << m_run init so masked lanes give p = 0
constexpr float DEFER_THR = 8.0f;

typedef _Float16 f16x2 __attribute__((ext_vector_type(2)));
typedef _Float16 f16x4 __attribute__((ext_vector_type(4)));
typedef _Float16 f16x8 __attribute__((ext_vector_type(8)));
typedef float    f32x4 __attribute__((ext_vector_type(4)));

__device__ __forceinline__ f16x2 pk2(float a, float b) {
    return __builtin_bit_cast(f16x2, __builtin_amdgcn_cvt_pkrtz(a, b));
}

// per-thread prefetch: 4 adjacent K rows + 4 adjacent V rows, one float4 col chunk
struct Pref {
    float4 k0, k1, k2, k3;
    float4 v0, v1, v2, v3;
};

__device__ __forceinline__ void load_tile(Pref& p, const float* __restrict__ kb,
                                          const float* __restrict__ vb,
                                          int kbase, int row4, int c4) {
    const size_t g = (size_t)(kbase + row4) * DIM + c4;
    p.k0 = *(const float4*)&kb[g + 0 * DIM];
    p.k1 = *(const float4*)&kb[g + 1 * DIM];
    p.k2 = *(const float4*)&kb[g + 2 * DIM];
    p.k3 = *(const float4*)&kb[g + 3 * DIM];
    p.v0 = *(const float4*)&vb[g + 0 * DIM];
    p.v1 = *(const float4*)&vb[g + 1 * DIM];
    p.v2 = *(const float4*)&vb[g + 2 * DIM];
    p.v3 = *(const float4*)&vb[g + 3 * DIM];
}

__device__ __forceinline__ void stage_tile(char* __restrict__ buf, const Pref& p,
                                           int row4, int c4) {
    _Float16* Ksh = (_Float16*)buf;
    _Float16* Vsh = (_Float16*)(buf + KBYTES);
    union { f16x4 v; f16x2 h[2]; } u;
    u.h[0] = pk2(p.k0.x, p.k0.y); u.h[1] = pk2(p.k0.z, p.k0.w);
    *(f16x4*)&Ksh[(row4 + 0) * KS + c4] = u.v;
    u.h[0] = pk2(p.k1.x, p.k1.y); u.h[1] = pk2(p.k1.z, p.k1.w);
    *(f16x4*)&Ksh[(row4 + 1) * KS + c4] = u.v;
    u.h[0] = pk2(p.k2.x, p.k2.y); u.h[1] = pk2(p.k2.z, p.k2.w);
    *(f16x4*)&Ksh[(row4 + 2) * KS + c4] = u.v;
    u.h[0] = pk2(p.k3.x, p.k3.y); u.h[1] = pk2(p.k3.z, p.k3.w);
    *(f16x4*)&Ksh[(row4 + 3) * KS + c4] = u.v;
    // V panels: panel = key>>4, within-panel key = key&15; 4 adjacent keys at
    // fixed d -> one 8B f16x4 store; row stride 20 f16 -> conflict-light reads
    const int pbase = (row4 >> 4) * (DIM * VSP) + (row4 & 15);
    const float* f0 = (const float*)&p.v0;
    const float* f1 = (const float*)&p.v1;
    const float* f2 = (const float*)&p.v2;
    const float* f3 = (const float*)&p.v3;
    #pragma unroll
    for (int j = 0; j < 4; ++j) {
        u.h[0] = pk2(f0[j], f1[j]);
        u.h[1] = pk2(f2[j], f3[j]);
        *(f16x4*)&Vsh[pbase + (c4 + j) * VSP] = u.v;
    }
}

// (256,2): blocks/CU semantics -> 8 waves/CU -> 256 VGPR cap; waves/EU -> same.
// Harmless cap either way (we need ~150 VGPR, 2 blocks/CU by LDS).
__global__ __launch_bounds__(NTHREADS, 2)
void swa_kernel(const float* __restrict__ qg, const float* __restrict__ kg,
                const float* __restrict__ vg, float* __restrict__ outg) {
    __shared__ __align__(16) char smem[SMEMBYTES];
    float* Osh = (float*)smem;

    const int tid  = threadIdx.x;
    const int lane = tid & 63;
    const int wave = tid >> 6;     // 0..3
    const int lr   = lane & 15;
    const int quad = lane >> 4;

    // chunked XCD swizzle: 4 consecutive qblks of one batch per XCD chunk
    static_assert(SEQ / BM == 32 && BATCH == 16, "swizzle assumes 512 blocks");
    const int lin    = blockIdx.x + (SEQ / BM) * blockIdx.y;  // 0..511
    const int xcd    = lin & 7;
    const int slot   = lin >> 3;
    const int member = slot & 3;
    const int gchunk = (slot >> 2) * 8 + xcd;  // bijective
    const int b      = gchunk >> 3;
    const int qblk   = (gchunk & 7) * 4 + member;

    const int qrow0 = qblk * BM;
    const int wr0   = qrow0 + wave * 32;          // 32 q-rows per wave
    const int q0    = wr0 + lr;                   // qt=0 lane q
    const int q1    = wr0 + 16 + lr;              // qt=1 lane q

    const float* qb = qg + (size_t)b * SEQ * DIM;
    const float* kb = kg + (size_t)b * SEQ * DIM;
    const float* vb = vg + (size_t)b * SEQ * DIM;
    float*       ob = outg + (size_t)b * SEQ * DIM;

    const int row4 = (tid >> 4) * 4;      // staging: 4 adjacent rows / thread
    const int c4   = (tid & 15) * 4;

    // ---- Q B-frags for both q-tiles, straight from global ----
    f16x8 qf0[2], qf1[2];
    #pragma unroll
    for (int qt = 0; qt < 2; ++qt) {
        const float* qp = qb + (size_t)(wr0 + qt * 16 + lr) * DIM + quad * 8;
        const float4 a0 = *(const float4*)(qp + 0);
        const float4 a1 = *(const float4*)(qp + 4);
        const float4 a2 = *(const float4*)(qp + 32);
        const float4 a3 = *(const float4*)(qp + 36);
        union { f16x8 v; f16x2 h[4]; } u0, u1;
        u0.h[0] = pk2(a0.x * QSCALE, a0.y * QSCALE);
        u0.h[1] = pk2(a0.z * QSCALE, a0.w * QSCALE);
        u0.h[2] = pk2(a1.x * QSCALE, a1.y * QSCALE);
        u0.h[3] = pk2(a1.z * QSCALE, a1.w * QSCALE);
        u1.h[0] = pk2(a2.x * QSCALE, a2.y * QSCALE);
        u1.h[1] = pk2(a2.z * QSCALE, a2.w * QSCALE);
        u1.h[2] = pk2(a3.x * QSCALE, a3.y * QSCALE);
        u1.h[3] = pk2(a3.z * QSCALE, a3.w * QSCALE);
        qf0[qt] = u0.v; qf1[qt] = u1.v;
    }

    f32x4 o[2][4];
    #pragma unroll
    for (int qt = 0; qt < 2; ++qt)
        #pragma unroll
        for (int mi = 0; mi < 4; ++mi) o[qt][mi] = (f32x4){0.f, 0.f, 0.f, 0.f};
    float m_run[2] = {-1e30f, -1e30f};
    float l_run[2] = {0.f, 0.f};

    const int t0 = (qrow0 > (WIN - 1)) ? (qrow0 - (WIN - 1)) >> 6 : 0;
    const int t1 = (qrow0 + BM - 1) >> 6;

    Pref pf;
    load_tile(pf, kb, vb, t0 * BN, row4, c4);
    stage_tile(smem, pf, row4, c4);
    __syncthreads();

    for (int t = t0; t <= t1; ++t) {
        const int cb = (t - t0) & 1;
        const _Float16* Kc = (const _Float16*)(smem + cb * BUFBYTES);
        const _Float16* Vc = (const _Float16*)(smem + cb * BUFBYTES + KBYTES);
        const bool have_next = (t < t1);

        if (have_next) load_tile(pf, kb, vb, (t + 1) * BN, row4, c4);
        __builtin_amdgcn_sched_barrier(0);   // pin prefetch issue point

        const int kbase = t * BN;
        // wave-uniform active m-tile range; q rows wr0..wr0+31
        const int u    = (wr0 - kbase) >> 4;          // multiple-of-2, may be <0
        const int mtlo = (u - 32 > 0) ? u - 32 : 0;
        const int mthi = (u + 1 < 3) ? u + 1 : 3;

        if (mtlo <= mthi) {
            // ---- S^T = K * Q^T: K-frag read ONCE, used by both q-tiles ----
            f32x4 sc[2][4];
            __builtin_amdgcn_s_setprio(1);
            #pragma unroll
            for (int mt = 0; mt < 4; ++mt) {
                if (mt >= mtlo && mt <= mthi) {
                    const f16x8 kf0 = *(const f16x8*)&Kc[(mt * 16 + lr) * KS + quad * 8];
                    const f16x8 kf1 = *(const f16x8*)&Kc[(mt * 16 + lr) * KS + 32 + quad * 8];
                    #pragma unroll
                    for (int qt = 0; qt < 2; ++qt) {
                        f32x4 s = (f32x4){0.f, 0.f, 0.f, 0.f};
                        s = __builtin_amdgcn_mfma_f32_16x16x32_f16(kf0, qf0[qt], s, 0, 0, 0);
                        s = __builtin_amdgcn_mfma_f32_16x16x32_f16(kf1, qf1[qt], s, 0, 0, 0);
                        sc[qt][mt] = s;
                    }
                }
            }
            __builtin_amdgcn_s_setprio(0);

            // ---- mask on window-edge rounds only (wave-uniform) ----
            const bool edge = ((wr0 + 31) - (kbase + mtlo * 16) >= WIN) ||
                              ((kbase + mthi * 16 + 15) > wr0);
            if (edge) {
                #pragma unroll
                for (int mt = 0; mt < 4; ++mt) {
                    if (mt >= mtlo && mt <= mthi) {
                        #pragma unroll
                        for (int r = 0; r < 4; ++r) {
                            const int key = kbase + mt * 16 + quad * 4 + r;
                            sc[0][mt][r] = ((unsigned)(q0 - key) < (unsigned)WIN) ? sc[0][mt][r] : MASKVAL;
                            sc[1][mt][r] = ((unsigned)(q1 - key) < (unsigned)WIN) ? sc[1][mt][r] : MASKVAL;
                        }
                    }
                }
            }

            // ---- online softmax per q-tile ----
            f16x4 pb[2][4];
            #pragma unroll
            for (int qt = 0; qt < 2; ++qt) {
                float pm = MASKVAL;
                #pragma unroll
                for (int mt = 0; mt < 4; ++mt) {
                    if (mt >= mtlo && mt <= mthi) {
                        pm = fmaxf(pm, fmaxf(fmaxf(sc[qt][mt][0], sc[qt][mt][1]),
                                             fmaxf(sc[qt][mt][2], sc[qt][mt][3])));
                    }
                }
                pm = fmaxf(pm, __shfl_xor(pm, 16));
                pm = fmaxf(pm, __shfl_xor(pm, 32));

                if (__any(pm > m_run[qt] + DEFER_THR)) {   // T13 defer-rescale
                    const float mn    = fmaxf(m_run[qt], pm);
                    const float alpha = exp2f(m_run[qt] - mn);
                    m_run[qt] = mn;
                    l_run[qt] *= alpha;
                    #pragma unroll
                    for (int mi = 0; mi < 4; ++mi) o[qt][mi] = o[qt][mi] * alpha;
                }

                float ls = 0.f;
                #pragma unroll
                for (int nt = 0; nt < 4; ++nt) {
                    if (nt >= mtlo && nt <= mthi) {
                        const float p0 = exp2f(sc[qt][nt][0] - m_run[qt]);
                        const float p1 = exp2f(sc[qt][nt][1] - m_run[qt]);
                        const float p2 = exp2f(sc[qt][nt][2] - m_run[qt]);
                        const float p3 = exp2f(sc[qt][nt][3] - m_run[qt]);
                        ls += (p0 + p1) + (p2 + p3);
                        union { f16x4 v; f16x2 h[2]; } up;
                        up.h[0] = pk2(p0, p1);
                        up.h[1] = pk2(p2, p3);
                        pb[qt][nt] = up.v;
                    }
                }
                l_run[qt] += ls;
            }

            // ---- O^T += V^T * P^T: V-frag read ONCE, used by both q-tiles ----
            __builtin_amdgcn_s_setprio(1);
            #pragma unroll
            for (int nt = 0; nt < 4; ++nt) {
                if (nt >= mtlo && nt <= mthi) {
                    #pragma unroll
                    for (int mi = 0; mi < 4; ++mi) {
                        const f16x4 vf = *(const f16x4*)&Vc[nt * (DIM * VSP)
                                             + (mi * 16 + lr) * VSP + quad * 4];
                        o[0][mi] = __builtin_amdgcn_mfma_f32_16x16x16f16(vf, pb[0][nt], o[0][mi], 0, 0, 0);
                        o[1][mi] = __builtin_amdgcn_mfma_f32_16x16x16f16(vf, pb[1][nt], o[1][mi], 0, 0, 0);
                    }
                }
            }
            __builtin_amdgcn_s_setprio(0);
        }

        if (have_next) stage_tile(smem + (cb ^ 1) * BUFBYTES, pf, row4, c4);
        __syncthreads();
    }

    // ---- epilogue per q-tile: l reduce, normalize, LDS transpose, store ----
    #pragma unroll
    for (int qt = 0; qt < 2; ++qt) {
        float l = l_run[qt];
        l += __shfl_xor(l, 16);
        l += __shfl_xor(l, 32);
        const float inv = 1.0f / l;
        float* Ow = Osh + (wave * 32 + qt * 16) * OS;   // per-wave-tile private region
        #pragma unroll
        for (int mi = 0; mi < 4; ++mi) {
            float4 st;
            st.x = o[qt][mi][0] * inv; st.y = o[qt][mi][1] * inv;
            st.z = o[qt][mi][2] * inv; st.w = o[qt][mi][3] * inv;
            *(float4*)&Ow[lr * OS + mi * 16 + quad * 4] = st;
        }
        #pragma unroll
        for (int j = 0; j < 4; ++j) {
            const int qq = quad + 4 * j;
            const int d4 = lr * 4;
            const float4 vst = *(const float4*)&Ow[qq * OS + d4];
            *(float4*)&ob[(size_t)(wr0 + qt * 16 + qq) * DIM + d4] = vst;
        }
    }
}

extern "C" void kernel_launch(void* const* d_in, const int* in_sizes, int n_in,
                              void* d_out, int out_size, void* d_ws, size_t ws_size,
                              hipStream_t stream) {
    (void)in_sizes; (void)n_in; (void)out_size; (void)d_ws; (void)ws_size;
    const float* q = (const float*)d_in[0];
    const float* k = (const float*)d_in[1];
    const float* v = (const float*)d_in[2];
    float* out = (float*)d_out;
    dim3 grid(SEQ / BM, BATCH);
    swa_kernel<<<grid, dim3(NTHREADS), 0, stream>>>(q, k, v, out);
}